// Round 5
// baseline (201.866 us; speedup 1.0000x reference)
//
#include <hip/hip_runtime.h>
#include <hip/hip_cooperative_groups.h>

#define HW    3136   // 56*56
#define HW4   784    // float4 per (b,c) row
#define C     512
#define B     32
#define ROWS  (B * C)          // 16384
#define RPB   16               // rows per block
#define NBLK  (ROWS / RPB)     // 1024 blocks -> 4 blocks/CU on 256 CUs

typedef float floatx4 __attribute__((ext_vector_type(4)));

// Single cooperative kernel: phase 1 row-means -> grid sync -> phase 2 gate+scale.
// Block owns 16 consecutive rows (same b, same modality m since 16 | 64).
// Phase 2 re-reads exactly the bytes this block read in phase 1 (L1/L2/L3-warm);
// out is stored non-temporal so the write stream doesn't evict x from L3.
__global__ __launch_bounds__(256, 4) void se_fused_kernel(const float* __restrict__ x,
                                                          const float* __restrict__ W,
                                                          const float* __restrict__ bias,
                                                          float* __restrict__ y,
                                                          float* __restrict__ out) {
    const int wave = threadIdx.x >> 6;
    const int lane = threadIdx.x & 63;
    const int row0 = blockIdx.x * RPB;

    // ---- phase 1: means of this block's 16 rows (4 rows per wave) ----
    #pragma unroll
    for (int r = 0; r < 4; ++r) {
        const int row = row0 + wave * 4 + r;
        const floatx4* xr = reinterpret_cast<const floatx4*>(x) + (size_t)row * HW4;
        float s = 0.f;
        for (int i = lane; i < HW4; i += 64) {
            floatx4 v = xr[i];
            s += (v.x + v.y) + (v.z + v.w);
        }
        #pragma unroll
        for (int off = 32; off; off >>= 1) s += __shfl_down(s, off, 64);
        if (lane == 0) y[row] = s * (1.0f / HW);
    }

    cooperative_groups::this_grid().sync();

    // ---- phase 2: one gate per block, computed redundantly per wave ----
    const int b = row0 >> 9;              // row0 / 512
    const int m = (row0 & (C - 1)) >> 6;  // modality of all 16 rows
    const float* yb = y + b * C;
    const float* wm = W + m * C;
    float s = 0.f;
    #pragma unroll
    for (int i = 0; i < 8; ++i) s = fmaf(yb[lane + 64 * i], wm[lane + 64 * i], s);
    #pragma unroll
    for (int off = 32; off; off >>= 1) s += __shfl_xor(s, off, 64);
    s += bias[m];
    s = fmaxf(s, 0.f);                          // relu
    const float g = 1.0f / (1.0f + expf(-s));   // sigmoid

    // ---- scale this block's own 16 rows (reads are cache-warm) ----
    #pragma unroll
    for (int r = 0; r < 4; ++r) {
        const int row = row0 + wave * 4 + r;
        const floatx4* xr  = reinterpret_cast<const floatx4*>(x) + (size_t)row * HW4;
        floatx4*      orow = reinterpret_cast<floatx4*>(out)     + (size_t)row * HW4;
        for (int i = lane; i < HW4; i += 64) {
            floatx4 v = xr[i];
            v *= g;
            __builtin_nontemporal_store(v, &orow[i]);
        }
    }
}

extern "C" void kernel_launch(void* const* d_in, const int* in_sizes, int n_in,
                              void* d_out, int out_size, void* d_ws, size_t ws_size,
                              hipStream_t stream) {
    const float* x    = (const float*)d_in[0];  // (32,512,56,56)
    const float* W    = (const float*)d_in[1];  // (8,512)
    const float* bias = (const float*)d_in[2];  // (8,)
    float* out = (float*)d_out;
    float* y   = (float*)d_ws;                  // 16384 floats = 64 KB

    void* args[] = { (void*)&x, (void*)&W, (void*)&bias, (void*)&y, (void*)&out };
    hipLaunchCooperativeKernel((const void*)se_fused_kernel,
                               dim3(NBLK), dim3(256), args, 0, stream);
}